// Round 11
// baseline (6337.299 us; speedup 1.0000x reference)
//
#include <hip/hip_runtime.h>
#include <stdint.h>

#define TT 128
#define BB 128
#define NN 1024
#define ZROW 1024      // index of the all-zero pad row appended to WtBf
#define PSTRIDE 384    // per-panel list stride (entries); %8==0 -> 768B, 16B-aligned

// World model (verified bit-exact in R9/R10):
//   tx: packed bf16 storage (runtime-probed), W: f32 storage with bf16-rounded
//   values (repacked to bf16 in ws; dirty-flag fallback to f32), b: f32,
//   out: f32. Reference recurrent sum: OpenBLAS sgemm kc=384 K-panels,
//   sequential-k single accumulator per panel, a = (P0 + P1) + P2. Binary y
//   makes every product exact, so this association is reproduced exactly.
//   Pad rows (k=ZROW) are all-zero: acc += 0.0f is bit-neutral (only the
//   sign of an exact-zero acc could differ, which cannot affect any v/spike).

__device__ __forceinline__ float bfbits2f(uint32_t lo16) {
  union { uint32_t i; float f; } c;
  c.i = lo16 << 16;
  return c.f;
}

// ---------------------------------------------------------------------------
// Kernel 0: in-place f32 transpose of W (tile-pair swap) + bf16 repack of W^T
// into ws + losslessness check (dirty flag) + zero pad-row (k=ZROW) fill.
// ---------------------------------------------------------------------------
__global__ __launch_bounds__(256) void w_transpose_repack(
    float* __restrict__ W, uint16_t* __restrict__ WtBf,
    uint32_t* __restrict__ dirty) {
  __shared__ float ta[32][33];
  __shared__ float tb[32][33];

  if (blockIdx.x == 0) {  // zero pad-row: WtBf[ZROW*NN .. +NN)
#pragma unroll
    for (int i = 0; i < 4; ++i)
      WtBf[ZROW * NN + threadIdx.x + i * 256] = 0;
  }

  int rem = blockIdx.x;
  int I = 0;
  while (rem >= (32 - I)) { rem -= (32 - I); ++I; }
  const int J = I + rem;

  const int lx = threadIdx.x & 31;
  const int ly = threadIdx.x >> 5;  // 0..7
  uint32_t bad = 0;

  if (I == J) {
#pragma unroll
    for (int i = 0; i < 4; ++i)
      ta[ly + i * 8][lx] = W[(I * 32 + ly + i * 8) * NN + J * 32 + lx];
    __syncthreads();
#pragma unroll
    for (int i = 0; i < 4; ++i) {
      const int idx = (I * 32 + ly + i * 8) * NN + J * 32 + lx;
      const float v = ta[lx][ly + i * 8];
      const uint32_t bits = __float_as_uint(v);
      W[idx] = v;
      WtBf[idx] = (uint16_t)(bits >> 16);
      bad |= (bits & 0xFFFFu);
    }
  } else {
#pragma unroll
    for (int i = 0; i < 4; ++i) {
      ta[ly + i * 8][lx] = W[(I * 32 + ly + i * 8) * NN + J * 32 + lx];
      tb[ly + i * 8][lx] = W[(J * 32 + ly + i * 8) * NN + I * 32 + lx];
    }
    __syncthreads();
#pragma unroll
    for (int i = 0; i < 4; ++i) {
      const int idxA = (J * 32 + ly + i * 8) * NN + I * 32 + lx;
      const float va = ta[lx][ly + i * 8];
      const uint32_t bitsA = __float_as_uint(va);
      W[idxA] = va;
      WtBf[idxA] = (uint16_t)(bitsA >> 16);
      bad |= (bitsA & 0xFFFFu);

      const int idxB = (I * 32 + ly + i * 8) * NN + J * 32 + lx;
      const float vb = tb[lx][ly + i * 8];
      const uint32_t bitsB = __float_as_uint(vb);
      W[idxB] = vb;
      WtBf[idxB] = (uint16_t)(bitsB >> 16);
      bad |= (bitsB & 0xFFFFu);
    }
  }
  const unsigned long long bm = __ballot(bad != 0);
  if ((threadIdx.x & 63) == 0 && bm) atomicOr(dirty, 1u);
}

// ---------------------------------------------------------------------------
// Kernel 1: per-sample LIF, 1024 threads (1 neuron/thread, 16 waves/CU).
// Per step: ballot -> per-panel compacted lists in LDS (3 segments, each
// 16B-aligned, padded to x8 with ZROW), ONE ds_read_b128 per 8 indices
// (prefetched), 8 saddr ushort loads in flight, sequential f32 adds in
// ascending k within each kc=384 panel (exact reference association).
// Double-buffered lists -> 2 barriers/step.
// ---------------------------------------------------------------------------
__global__ __launch_bounds__(1024) void lif_persample(
    const void* __restrict__ tx_raw, const float* __restrict__ bias,
    const float* __restrict__ WtF32, const uint16_t* __restrict__ WtBf,
    const uint32_t* __restrict__ dirty, float* __restrict__ out) {
  const int b = blockIdx.x;
  const int tid = threadIdx.x;     // == neuron index n == recurrent index k
  const int lane = tid & 63;
  const int wv = tid >> 6;         // 0..15
  const int panel = (wv < 6) ? 0 : (wv < 12 ? 1 : 2);

  __shared__ __align__(16) uint16_t lst[2][3 * PSTRIDE];
  __shared__ int wcnt[2][16];
  __shared__ int sprobe;

  // ---- runtime tx-storage probe (bf16-packed vs f32), verified R9/R10 ----
  if (tid == 0) sprobe = 0;
  __syncthreads();
  {
    const uint32_t* txw = (const uint32_t*)tx_raw;
    int local = 0;
#pragma unroll
    for (int i = 0; i < 2; ++i) {
      const uint32_t f = (txw[tid * 2 + i] >> 7) & 0xFFu;
      local += (f >= 0x74u && f < 0x81u) ? 1 : 0;
    }
    atomicAdd(&sprobe, local);
  }
  __syncthreads();
  const bool tx_is_bf16 = (sprobe > 1024);   // of 2048 sampled words
  const bool w_bf = (*dirty == 0u);          // bf16 repack lossless?

  const uint16_t* __restrict__ txh = (const uint16_t*)tx_raw;
  const float* __restrict__ txf = (const float*)tx_raw;
  const float bz = bias[tid];

  float v = 0.0f;   // membrane (REST = 0)
  int y = 0;        // previous spike

  for (int t = 0; t < TT; ++t) {
    const int buf = t & 1;

    // ---- ballot + per-wave counts ----
    const unsigned long long m = __ballot(y);
    if (lane == 0) wcnt[buf][wv] = __popcll(m);
    __syncthreads();  // SYNC1: wcnt visible

    // ---- prefixes / panel counts (all uniform within the block) ----
    int g = 0, c0 = 0, c1 = 0, c2 = 0;
#pragma unroll
    for (int w = 0; w < 16; ++w) {
      const int cc = wcnt[buf][w];
      g += (w < wv) ? cc : 0;
      if (w < 6) c0 += cc;
      else if (w < 12) c1 += cc;
      else c2 += cc;
    }
    const int pstart = (panel == 0) ? 0 : ((panel == 1) ? c0 : c0 + c1);

    // ---- write compacted list entries (ascending k within each panel) ----
    if (y) {
      const int below = __builtin_amdgcn_mbcnt_hi(
          (uint32_t)(m >> 32), __builtin_amdgcn_mbcnt_lo((uint32_t)m, 0));
      lst[buf][panel * PSTRIDE + (g - pstart) + below] = (uint16_t)tid;
    }
    // ---- pad each panel to a multiple of 8 with the zero row ----
    if (tid < 24) {
      const int p = tid >> 3, j = tid & 7;
      const int cp = (p == 0) ? c0 : ((p == 1) ? c1 : c2);
      if (j < ((8 - (cp & 7)) & 7))
        lst[buf][p * PSTRIDE + cp + j] = (uint16_t)ZROW;
    }
    __syncthreads();  // SYNC2: lists complete

    // ---- gather: (P0 + P1) + P2, sequential k within each panel ----
    float a;
    if (w_bf) {
      auto gather = [&](int pbase, int cnt) -> float {
        float acc = 0.0f;
        const uint4* l4 = (const uint4*)&lst[buf][pbase];
        const int nb = (cnt + 7) >> 3;
        uint4 idx;
        if (nb > 0) idx = l4[0];
        for (int u = 0; u < nb; ++u) {
          const uint32_t a0 = __builtin_amdgcn_readfirstlane(idx.x);
          const uint32_t a1 = __builtin_amdgcn_readfirstlane(idx.y);
          const uint32_t a2 = __builtin_amdgcn_readfirstlane(idx.z);
          const uint32_t a3 = __builtin_amdgcn_readfirstlane(idx.w);
          if (u + 1 < nb) idx = l4[u + 1];   // prefetch next index vector
          const float w0 = bfbits2f((uint32_t)WtBf[(a0 & 0xffffu) * NN + tid]);
          const float w1 = bfbits2f((uint32_t)WtBf[(a0 >> 16) * NN + tid]);
          const float w2 = bfbits2f((uint32_t)WtBf[(a1 & 0xffffu) * NN + tid]);
          const float w3 = bfbits2f((uint32_t)WtBf[(a1 >> 16) * NN + tid]);
          const float w4 = bfbits2f((uint32_t)WtBf[(a2 & 0xffffu) * NN + tid]);
          const float w5 = bfbits2f((uint32_t)WtBf[(a2 >> 16) * NN + tid]);
          const float w6 = bfbits2f((uint32_t)WtBf[(a3 & 0xffffu) * NN + tid]);
          const float w7 = bfbits2f((uint32_t)WtBf[(a3 >> 16) * NN + tid]);
          acc += w0; acc += w1; acc += w2; acc += w3;
          acc += w4; acc += w5; acc += w6; acc += w7;
        }
        return acc;
      };
      const float p0 = gather(0, c0);
      const float p1 = gather(PSTRIDE, c1);
      const float p2 = gather(2 * PSTRIDE, c2);
      a = (p0 + p1) + p2;
    } else {
      // fallback (never taken when repack lossless): f32 rows, per-entry,
      // pads skipped by bounding at the true count.
      auto gatherf = [&](int pbase, int cnt) -> float {
        float acc = 0.0f;
        for (int i = 0; i < cnt; ++i) {
          const int k = __builtin_amdgcn_readfirstlane((int)lst[buf][pbase + i]);
          acc += WtF32[k * NN + tid];
        }
        return acc;
      };
      const float p0 = gatherf(0, c0);
      const float p1 = gatherf(PSTRIDE, c1);
      const float p2 = gatherf(2 * PSTRIDE, c2);
      a = (p0 + p1) + p2;
    }

    // ---- LIF update, reference op order, f32 ----
    const int off = (t * BB + b) * NN + tid;
    const float xx = tx_is_bf16 ? bfbits2f((uint32_t)txh[off]) : txf[off];
    const float xv = (xx + a) + bz;
    v = (y ? 0.0f : 0.5f * v) + xv;
    y = (v > 0.5f);

    out[off] = y ? 1.0f : 0.0f;
    // no trailing barrier: next step writes buf^1; SYNC1(t+1) orders it
    // after every wave's gather of step t.
  }
}

extern "C" void kernel_launch(void* const* d_in, const int* in_sizes, int n_in,
                              void* d_out, int out_size, void* d_ws, size_t ws_size,
                              hipStream_t stream) {
  // Inputs by element count: tx = 128*128*1024 (bf16-packed),
  // W = 1024*1024 (f32, bf16-valued), b = 1024 (f32).
  const void* tx = nullptr;
  float* W = nullptr;
  const float* bs = nullptr;
  for (int i = 0; i < n_in; ++i) {
    if (in_sizes[i] == TT * BB * NN) tx = d_in[i];
    else if (in_sizes[i] == NN * NN) W = (float*)d_in[i];
    else if (in_sizes[i] == NN) bs = (const float*)d_in[i];
  }
  float* out = (float*)d_out;                       // [T, B, N] f32 spikes

  uint16_t* WtBf = (uint16_t*)d_ws;                 // (NN+1)*NN bf16 = 2 MB + 2 KB
  uint32_t* dirty = (uint32_t*)((char*)d_ws + 3u * 1024u * 1024u);

  // ws is poisoned 0xAA each launch — clear the dirty flag first.
  hipMemsetAsync(dirty, 0, sizeof(uint32_t), stream);

  w_transpose_repack<<<dim3(528), dim3(256), 0, stream>>>(W, WtBf, dirty);
  lif_persample<<<dim3(BB), dim3(1024), 0, stream>>>(tx, bs, W, WtBf, dirty, out);
}